// Round 15
// baseline (1946.109 us; speedup 1.0000x reference)
//
#include <hip/hip_runtime.h>

#define HID 768
#define WPB 32     // words per tile (M = 128 rows)
#define MROWS 128
#define NCH 12     // K-chunks of 64
#define NSTRIP 6   // 6 col-strips x 128 cols

typedef __attribute__((ext_vector_type(4))) float f32x4;
typedef __attribute__((ext_vector_type(8))) short s16x8;
typedef __attribute__((ext_vector_type(4))) short s16x4;

__device__ inline short f2bf(float f) {
  unsigned u = __builtin_bit_cast(unsigned, f);
  u = (u + 0x7fffu + ((u >> 16) & 1u)) >> 16;
  return (short)(unsigned short)u;
}
__device__ inline float fast_tanh(float v) {
  float e = exp2f(v * 2.885390081777927f);   // e^{2v}
  return 1.0f - 2.0f * __builtin_amdgcn_rcpf(e + 1.0f);
}
__device__ inline s16x8 pack8(f32x4 f0, f32x4 f1) {
  s16x8 p;
  p[0]=f2bf(f0[0]); p[1]=f2bf(f0[1]); p[2]=f2bf(f0[2]); p[3]=f2bf(f0[3]);
  p[4]=f2bf(f1[0]); p[5]=f2bf(f1[1]); p[6]=f2bf(f1[2]); p[7]=f2bf(f1[3]);
  return p;
}
__device__ inline s16x4 pack4(f32x4 f) {
  s16x4 p;
  p[0]=f2bf(f[0]); p[1]=f2bf(f[1]); p[2]=f2bf(f[2]); p[3]=f2bf(f[3]);
  return p;
}

// ---- pre-pass: W fp32 -> bf16 in MFMA FRAGMENT ORDER (verified r7-r14) ----
// frag(kc, t): k-chunk kc (32 wide), col-tile t (16 wide); 64 lanes x 16B
// contiguous (1 KB). Lane l holds W[t*16 + (l&15)][kc*32 + (l>>4)*8 .. +8].
__global__ void wconv_kernel(const float* __restrict__ W, short* __restrict__ Wb, int n64) {
  int gid = blockIdx.x * blockDim.x + threadIdx.x;
  if (gid >= n64) return;                  // 24*48*64 = 73728
  int lane = gid & 63;
  int frag = gid >> 6;
  int kc = frag / 48;
  int t  = frag - kc * 48;
  int col = t * 16 + (lane & 15);
  int k0  = kc * 32 + (lane >> 4) * 8;
  const float* src = W + (size_t)col * HID + k0;
  f32x4 f0 = *(const f32x4*)src;
  f32x4 f1 = *(const f32x4*)(src + 4);
  *(s16x8*)(Wb + (size_t)gid * 8) = pack8(f0, f1);
}

// ==== main: m97-structure. 128x128 tiles, 4-wave blocks, 2 blocks/CU,
//      B staged via global_load_lds, A reg-staged+cvt, 1 barrier/chunk ====
__global__ __launch_bounds__(256, 2) void gemm_97(
    const float* __restrict__ x, const short* __restrict__ Wb,
    const float* __restrict__ bias, const float* __restrict__ scw,
    const int* __restrict__ mapping, float* __restrict__ out,
    int num_words, float* __restrict__ s_glob, int* __restrict__ cnt, int swz)
{
  __shared__ short Abuf[2 * 8192];   // 32 KB: A 128x64 bf16, verified swizzle, dbuf
  __shared__ short Bbuf[2 * 8192];   // 32 KB: B 16 frags x 1KB, linear, dbuf
  __shared__ float s_lds[MROWS];
  __shared__ int lastflag;

  const int tid = threadIdx.x;
  int tile, strip;
  if (swz) {                         // 6 strip-siblings differ by 8 in blockIdx
    int q = blockIdx.x / 48;         // -> same XCD -> A shared in L2 (r13 ✓)
    int rr = blockIdx.x - q * 48;
    tile = q * 8 + (rr & 7);
    strip = rr >> 3;
  } else {
    tile = blockIdx.x / NSTRIP;
    strip = blockIdx.x - tile * NSTRIP;
  }
  const int w0 = tile * WPB;
  const int wlast = min(w0 + WPB - 1, num_words - 1);
  const int r0 = mapping[2 * w0];
  const int r1 = mapping[2 * wlast + 1];
  const int nrows = min(r1 - r0, MROWS);

  // A staging map (r9/r13-verified, 0 conflicts): 16 thr/row, 8 row-groups
  const int arow = tid >> 4;         // 0..15
  const int aslot = tid & 15;
  const float* xs = x + (size_t)(r0 + arow) * HID + aslot * 4;
  const int lofs = arow * 128 + ((aslot * 8) ^ ((arow & 7) << 4));
  bool rok[8];
  #pragma unroll
  for (int i = 0; i < 8; ++i) rok[i] = (arow + 16 * i) < nrows;

  if (tid < MROWS) s_lds[tid] = 0.0f;

  // MFMA geometry: 4 waves = 2M x 2N; wave-tile 64 rows x 64 cols
  const int lane = tid & 63;
  const int wave = tid >> 6;         // 0..3
  const int mw = wave >> 1;          // 0..1
  const int nw = wave & 1;           // 0..1
  const int l15 = lane & 15;
  const int lk  = lane >> 4;
  const int col0 = (lk * 16) ^ ((l15 & 7) << 4);
  const int col1 = col0 ^ 64;

  f32x4 acc[4][4];
  #pragma unroll
  for (int m = 0; m < 4; ++m)
    #pragma unroll
    for (int n = 0; n < 4; ++n) acc[m][n] = (f32x4){0,0,0,0};

  f32x4 pa[8];

  // B staging: 16 frags (2 k-halves x 8 col-tiles) per chunk; wave w stages
  // frags s = w*4..w*4+3 via global_load_lds width=16 (dest wave-uniform,
  // source per-lane -> one coalesced 1KB transfer each, no VGPR round-trip)
  #define B_GLDS(BUF, CH) do { _Pragma("unroll") for (int i_ = 0; i_ < 4; ++i_) { \
      int s_ = wave * 4 + i_; \
      const short* g_ = Wb + ((size_t)((2 * (CH) + (s_ >> 3)) * 48 + strip * 8 + (s_ & 7))) * 512 + lane * 8; \
      unsigned off_ = __builtin_amdgcn_readfirstlane((unsigned)((BUF) * 16384 + s_ * 1024)); \
      __builtin_amdgcn_global_load_lds( \
          (const __attribute__((address_space(1))) void*)g_, \
          (__attribute__((address_space(3))) void*)((char*)Bbuf + off_), 16, 0, 0); \
    } } while(0)

  #define A_ISS(CH) do { _Pragma("unroll") for (int i_ = 0; i_ < 8; ++i_) \
      pa[i_] = rok[i_] ? *(const f32x4*)(xs + (size_t)(16 * i_) * HID + (CH) * 64) \
                       : (f32x4){0,0,0,0}; } while(0)

  #define A_WRT(BUF) do { _Pragma("unroll") for (int i_ = 0; i_ < 8; ++i_) \
      *(s16x4*)((char*)Abuf + (BUF) * 16384 + lofs + i_ * 2048) = pack4(pa[i_]); } while(0)

  // ---- prologue: chunk 0 staged ----
  B_GLDS(0, 0);
  A_ISS(0);
  A_WRT(0);
  __syncthreads();

  // ---- K loop: m97 2-barrier-per-chunk structure (1 __syncthreads here;
  //      the other block on the CU fills the drain stall - m114) ----
  #pragma unroll 1
  for (int ch = 0; ch < NCH; ++ch) {
    const int buf = ch & 1;
    const bool pre = (ch + 1 < NCH);
    if (pre) { B_GLDS(buf ^ 1, ch + 1); A_ISS(ch + 1); }
    #pragma unroll
    for (int kk = 0; kk < 2; ++kk) {
      const short* bb = Bbuf + buf * 8192 + (kk * 8 + nw * 4) * 512 + lane * 8;
      s16x8 b0 = *(const s16x8*)(bb);
      s16x8 b1 = *(const s16x8*)(bb + 512);
      s16x8 b2 = *(const s16x8*)(bb + 1024);
      s16x8 b3 = *(const s16x8*)(bb + 1536);
      const char* ab = (const char*)Abuf + buf * 16384
                     + (mw * 64 + l15) * 128 + (kk ? col1 : col0);
      __builtin_amdgcn_s_setprio(1);
      #pragma unroll
      for (int m = 0; m < 4; ++m) {
        s16x8 a = *(const s16x8*)(ab + m * 2048);
        acc[m][0] = __builtin_amdgcn_mfma_f32_16x16x32_bf16(a, b0, acc[m][0], 0,0,0);
        acc[m][1] = __builtin_amdgcn_mfma_f32_16x16x32_bf16(a, b1, acc[m][1], 0,0,0);
        acc[m][2] = __builtin_amdgcn_mfma_f32_16x16x32_bf16(a, b2, acc[m][2], 0,0,0);
        acc[m][3] = __builtin_amdgcn_mfma_f32_16x16x32_bf16(a, b3, acc[m][3], 0,0,0);
      }
      __builtin_amdgcn_s_setprio(0);
    }
    if (pre) A_WRT(buf ^ 1);
    __syncthreads();
  }

  // --- tanh + scorer dot (wave's 64 cols of this 128-col strip) -> s_lds ---
  float wv[4], bv[4];
  #pragma unroll
  for (int n = 0; n < 4; ++n) {
    int col = strip * 128 + nw * 64 + n * 16 + l15;
    wv[n] = scw[col];
    bv[n] = bias[col];
  }
  #pragma unroll
  for (int m = 0; m < 4; ++m) {
    #pragma unroll
    for (int r = 0; r < 4; ++r) {
      float v = 0.0f;
      #pragma unroll
      for (int n = 0; n < 4; ++n)
        v += fast_tanh(acc[m][n][r] + bv[n]) * wv[n];
      v += __shfl_xor(v, 1);
      v += __shfl_xor(v, 2);
      v += __shfl_xor(v, 4);
      v += __shfl_xor(v, 8);
      if (l15 == 0) atomicAdd(&s_lds[mw * 64 + m * 16 + lk * 4 + r], v);
    }
  }
  __syncthreads();

  // publish strip partials, counter handshake (r11/r13-verified)
  if (tid < nrows) atomicAdd(&s_glob[r0 + tid], s_lds[tid]);
  __syncthreads();
  if (tid == 0) {
    __threadfence();
    int old = atomicAdd(&cnt[tile], 1);
    lastflag = (old == NSTRIP - 1) ? 1 : 0;
  }
  __syncthreads();
  if (!lastflag) return;
  __threadfence();

  if (tid < MROWS)
    s_lds[tid] = (tid < nrows)
        ? __hip_atomic_load(&s_glob[r0 + tid], __ATOMIC_RELAXED, __HIP_MEMORY_SCOPE_AGENT)
        : 0.0f;
  __syncthreads();

  // --- per-word softmax + weighted sum (x L2/L3-warm), 4 waves x 8 words ---
  const float LOG2E = 1.4426950408889634f;
  for (int wi = wave; wi < WPB; wi += 4) {
    int gw = w0 + wi;
    if (gw >= num_words) break;
    int grs = mapping[2 * gw];
    int lrs = grs - r0;
    int cnt_ = min(mapping[2 * gw + 1] - r0, nrows) - lrs;
    float mmax = -3.0e38f;
    for (int i = 0; i < cnt_; ++i) mmax = fmaxf(mmax, s_lds[lrs + i]);
    float denom = 0.0f;
    for (int i = 0; i < cnt_; ++i) denom += exp2f((s_lds[lrs + i] - mmax) * LOG2E);
    float rden = (denom > 0.0f) ? (1.0f / denom) : 0.0f;
    float pbuf[8];
    #pragma unroll
    for (int i = 0; i < 8; ++i)
      pbuf[i] = (i < cnt_) ? exp2f((s_lds[lrs + i] - mmax) * LOG2E) * rden : 0.0f;
    #pragma unroll
    for (int j = 0; j < 3; ++j) {
      int col = j * 256 + lane * 4;
      const float* xb = x + (size_t)grs * HID + col;
      f32x4 o = {0, 0, 0, 0};
      #pragma unroll
      for (int i = 0; i < 8; ++i) {
        if (i < cnt_) {
          f32x4 xv = *(const f32x4*)(xb + (size_t)i * HID);
          o[0] += pbuf[i] * xv[0];
          o[1] += pbuf[i] * xv[1];
          o[2] += pbuf[i] * xv[2];
          o[3] += pbuf[i] * xv[3];
        }
      }
      for (int i = 8; i < cnt_; ++i) {   // generality tail (unused for this data)
        float p = exp2f((s_lds[lrs + i] - mmax) * LOG2E) * rden;
        f32x4 xv = *(const f32x4*)(xb + (size_t)i * HID);
        o[0] += p * xv[0];
        o[1] += p * xv[1];
        o[2] += p * xv[2];
        o[3] += p * xv[3];
      }
      *(f32x4*)(out + (size_t)gw * HID + col) = o;
    }
  }
  #undef B_GLDS
  #undef A_ISS
  #undef A_WRT
}

// ==== fallback (fused 64-row kernel, fp32-B path) if workspace too small ====
__global__ __launch_bounds__(1024, 1) void fused_fb(
    const float* __restrict__ x, const float* __restrict__ Wf,
    const float* __restrict__ bias, const float* __restrict__ scw,
    const int* __restrict__ mapping, float* __restrict__ out, int num_words)
{
  __shared__ short Abuf[64 * 64];
  __shared__ float s_lds[64];
  const int tid = threadIdx.x;
  const int tile = blockIdx.x;
  const int w0 = tile * 16;
  const int wlast = min(w0 + 15, num_words - 1);
  const int r0 = mapping[2 * w0];
  const int r1 = mapping[2 * wlast + 1];
  const int nrows = min(r1 - r0, 64);
  const int srow = tid >> 4;
  const int sslot = tid & 15;
  const bool sok = srow < nrows;
  const float* xs = x + (size_t)(r0 + srow) * HID + sslot * 4;
  char* wsw = (char*)Abuf + srow * 128 + ((sslot * 8) ^ ((srow & 7) << 4));
  if (tid < 64) s_lds[tid] = 0.0f;
  const int lane = tid & 63;
  const int wave = tid >> 6;
  const int l15 = lane & 15;
  const int lk  = lane >> 4;
  const int c0  = wave * 48;
  const char* abase = (const char*)Abuf + l15 * 128;
  const int col0 = (lk * 16) ^ ((l15 & 7) << 4);
  const int col1 = col0 ^ 64;
  const float* Bf = Wf + (size_t)(c0 + l15) * HID + lk * 8;
  f32x4 acc[4][3];
  #pragma unroll
  for (int m = 0; m < 4; ++m)
    #pragma unroll
    for (int n = 0; n < 3; ++n) acc[m][n] = (f32x4){0,0,0,0};
  #pragma unroll 1
  for (int ch = 0; ch < NCH; ++ch) {
    f32x4 pfA = sok ? *(const f32x4*)(xs + ch * 64) : (f32x4){0,0,0,0};
    *(s16x4*)(wsw) = pack4(pfA);
    __syncthreads();
    #pragma unroll
    for (int kk = 0; kk < 2; ++kk) {
      const int kg = ch * 64 + kk * 32;
      s16x8 b[3];
      #pragma unroll
      for (int n = 0; n < 3; ++n) {
        f32x4 g0 = *(const f32x4*)(Bf + n * (16 * HID) + kg);
        f32x4 g1 = *(const f32x4*)(Bf + n * (16 * HID) + kg + 4);
        b[n] = pack8(g0, g1);
      }
      #pragma unroll
      for (int m = 0; m < 4; ++m) {
        s16x8 a = *(const s16x8*)(abase + m * 2048 + (kk ? col1 : col0));
        #pragma unroll
        for (int n = 0; n < 3; ++n)
          acc[m][n] = __builtin_amdgcn_mfma_f32_16x16x32_bf16(a, b[n], acc[m][n], 0,0,0);
      }
    }
    __syncthreads();
  }
  float wv[3], bv[3];
  #pragma unroll
  for (int n = 0; n < 3; ++n) {
    int col = c0 + n * 16 + l15;
    wv[n] = scw[col];
    bv[n] = bias[col];
  }
  #pragma unroll
  for (int m = 0; m < 4; ++m) {
    #pragma unroll
    for (int r = 0; r < 4; ++r) {
      float v = 0.0f;
      #pragma unroll
      for (int n = 0; n < 3; ++n)
        v += fast_tanh(acc[m][n][r] + bv[n]) * wv[n];
      v += __shfl_xor(v, 1);
      v += __shfl_xor(v, 2);
      v += __shfl_xor(v, 4);
      v += __shfl_xor(v, 8);
      if (l15 == 0) atomicAdd(&s_lds[m * 16 + lk * 4 + r], v);
    }
  }
  __syncthreads();
  const float LOG2E = 1.4426950408889634f;
  int gw = w0 + wave;
  if (wave < 16 && gw < num_words) {
    int grs = mapping[2 * gw];
    int lrs = grs - r0;
    int cnt_ = min(mapping[2 * gw + 1] - r0, nrows) - lrs;
    float mmax = -3.0e38f;
    for (int i = 0; i < cnt_; ++i) mmax = fmaxf(mmax, s_lds[lrs + i]);
    float denom = 0.0f;
    for (int i = 0; i < cnt_; ++i) denom += exp2f((s_lds[lrs + i] - mmax) * LOG2E);
    float rden = (denom > 0.0f) ? (1.0f / denom) : 0.0f;
    #pragma unroll
    for (int j = 0; j < 3; ++j) {
      int col = j * 256 + lane * 4;
      const float* xb = x + (size_t)grs * HID + col;
      f32x4 o = {0, 0, 0, 0};
      for (int i = 0; i < cnt_; ++i) {
        float p = exp2f((s_lds[lrs + i] - mmax) * LOG2E) * rden;
        f32x4 xv = *(const f32x4*)(xb + (size_t)i * HID);
        o[0] += p * xv[0]; o[1] += p * xv[1]; o[2] += p * xv[2]; o[3] += p * xv[3];
      }
      *(f32x4*)(out + (size_t)gw * HID + col) = o;
    }
  }
}

extern "C" void kernel_launch(void* const* d_in, const int* in_sizes, int n_in,
                              void* d_out, int out_size, void* d_ws, size_t ws_size,
                              hipStream_t stream) {
  const float* x    = (const float*)d_in[0];
  const float* W    = (const float*)d_in[1];
  const float* bias = (const float*)d_in[2];
  const float* scw  = (const float*)d_in[3];
  // d_in[4] (scorer bias) shifts every logit equally -> cancels in softmax
  const int* mapping = (const int*)d_in[5];
  float* out = (float*)d_out;

  int num_words = in_sizes[5] / 2;
  int n_sub = in_sizes[0] / HID;
  int ntiles = (num_words + WPB - 1) / WPB;

  size_t wb_bytes  = (size_t)HID * HID * sizeof(short);
  size_t sg_bytes  = (size_t)n_sub * sizeof(float);
  size_t cnt_bytes = (size_t)ntiles * sizeof(int);
  size_t need = wb_bytes + sg_bytes + cnt_bytes;

  char* wsb = (char*)d_ws;
  if (ws_size >= need) {
    short* Wb     = (short*)wsb;
    float* s_glob = (float*)(wsb + wb_bytes);
    int*   cntb   = (int*)(wsb + wb_bytes + sg_bytes);
    hipMemsetAsync(s_glob, 0, sg_bytes + cnt_bytes, stream);
    int n64 = (HID / 32) * (HID / 16) * 64;
    wconv_kernel<<<(n64 + 255) / 256, 256, 0, stream>>>(W, Wb, n64);
    int swz = (ntiles % 8 == 0) ? 1 : 0;
    gemm_97<<<ntiles * NSTRIP, 256, 0, stream>>>(
        x, Wb, bias, scw, mapping, out, num_words, s_glob, cntb, swz);
  } else {
    int nt16 = (num_words + 15) / 16;
    fused_fb<<<nt16, 1024, 0, stream>>>(x, W, bias, scw, mapping, out, num_words);
  }
}

// Round 16
// 1569.351 us; speedup vs baseline: 1.2401x; 1.2401x over previous
//
#include <hip/hip_runtime.h>

#define HID 768
#define WPB 64     // words per tile (M = 256 rows)
#define MROWS 256
#define BK 64
#define NCH 12     // 768 / 64
#define NSTRIP 4   // 4 col-strips x 192 cols

typedef __attribute__((ext_vector_type(4))) float f32x4;
typedef __attribute__((ext_vector_type(8))) short s16x8;
typedef __attribute__((ext_vector_type(4))) short s16x4;

__device__ inline short f2bf(float f) {
  unsigned u = __builtin_bit_cast(unsigned, f);
  u = (u + 0x7fffu + ((u >> 16) & 1u)) >> 16;
  return (short)(unsigned short)u;
}
__device__ inline float fast_tanh(float v) {
  float e = exp2f(v * 2.885390081777927f);   // e^{2v}
  return 1.0f - 2.0f * __builtin_amdgcn_rcpf(e + 1.0f);
}
__device__ inline s16x8 pack8(f32x4 f0, f32x4 f1) {
  s16x8 p;
  p[0]=f2bf(f0[0]); p[1]=f2bf(f0[1]); p[2]=f2bf(f0[2]); p[3]=f2bf(f0[3]);
  p[4]=f2bf(f1[0]); p[5]=f2bf(f1[1]); p[6]=f2bf(f1[2]); p[7]=f2bf(f1[3]);
  return p;
}
__device__ inline s16x4 pack4(f32x4 f) {
  s16x4 p;
  p[0]=f2bf(f[0]); p[1]=f2bf(f[1]); p[2]=f2bf(f[2]); p[3]=f2bf(f[3]);
  return p;
}

// ---- pre-pass: W fp32 -> bf16 in MFMA FRAGMENT ORDER (verified r7-r15) ----
// frag(kc, t): k-chunk kc (32 wide), col-tile t (16 wide); 64 lanes x 16B
// contiguous (1 KB). Lane l holds W[t*16 + (l&15)][kc*32 + (l>>4)*8 .. +8].
__global__ void wconv_kernel(const float* __restrict__ W, short* __restrict__ Wb, int n64) {
  int gid = blockIdx.x * blockDim.x + threadIdx.x;
  if (gid >= n64) return;                  // 24*48*64 = 73728
  int lane = gid & 63;
  int frag = gid >> 6;
  int kc = frag / 48;
  int t  = frag - kc * 48;
  int col = t * 16 + (lane & 15);
  int k0  = kc * 32 + (lane >> 4) * 8;
  const float* src = W + (size_t)col * HID + k0;
  f32x4 f0 = *(const f32x4*)src;
  f32x4 f1 = *(const f32x4*)(src + 4);
  *(s16x8*)(Wb + (size_t)gid * 8) = pack8(f0, f1);
}

// ==== main: r9 wave internals (16 waves, wave-tile 64x48, reg-pipelined B)
//      with block tile M=256 x 192-col strip -> B L2 traffic 4.8 -> 1.2 GB ====
__global__ __launch_bounds__(1024, 1) void gemm_m256(
    const float* __restrict__ x, const short* __restrict__ Wb,
    const float* __restrict__ bias, const float* __restrict__ scw,
    const int* __restrict__ mapping, float* __restrict__ out,
    int num_words, float* __restrict__ s_glob, int* __restrict__ cnt, int swz)
{
  __shared__ short Abuf[2 * MROWS * BK];   // 64 KB: A bf16, verified swizzle, dbuf
  __shared__ float s_lds[MROWS];
  __shared__ int lastflag;

  const int tid = threadIdx.x;
  int tile, strip;
  if (swz) {                               // strip-siblings differ by 8 in blockIdx
    int q = blockIdx.x / 32;               // -> same XCD -> A shared in L2 (r13 ✓)
    int rr = blockIdx.x - q * 32;
    tile = q * 8 + (rr & 7);
    strip = rr >> 3;
  } else {
    tile = blockIdx.x / NSTRIP;
    strip = blockIdx.x - tile * NSTRIP;
  }
  const int w0 = tile * WPB;
  const int wlast = min(w0 + WPB - 1, num_words - 1);
  const int r0 = mapping[2 * w0];
  const int r1 = mapping[2 * wlast + 1];
  const int nrows = min(r1 - r0, MROWS);

  // --- A staging: r12-verified 4-band map (0 conflicts): 16 thr/row,
  //     bands of 64 rows at +it*64; swizzle per row ---
  const int arow = tid >> 4;               // 0..63
  const int aslot = tid & 15;
  const float* xs = x + (size_t)(r0 + arow) * HID + aslot * 4;
  const int wofs = arow * 128 + ((aslot * 8) ^ ((arow & 7) << 4));
  bool rok[4];
  #pragma unroll
  for (int i = 0; i < 4; ++i) rok[i] = (arow + 64 * i) < nrows;

  if (tid < MROWS) s_lds[tid] = 0.0f;

  // --- MFMA geometry: 16 waves = 4M x 4N; wave-tile 64 rows x 48 cols (r9) ---
  const int lane = tid & 63;
  const int wave = tid >> 6;               // 0..15
  const int mw = wave >> 2;                // 0..3 M-band
  const int nw = wave & 3;                 // 0..3 N group
  const int l15 = lane & 15;
  const int lk  = lane >> 4;
  const char* abase = (const char*)Abuf + (mw * 64 + l15) * 128;
  const int col0 = (lk * 16) ^ ((l15 & 7) << 4);
  const int col1 = col0 ^ 64;

  // fragment-ordered B: this wave's col-tiles start at t = strip*12 + nw*3
  const short* B2 = Wb + (size_t)(strip * 12 + nw * 3) * 512 + lane * 8;
  auto loadB = [&](int n, int kc) -> s16x8 {   // kc = 32-wide chunk idx, 0..23
    return *(const s16x8*)(B2 + (size_t)kc * 24576 + n * 512);
  };

  f32x4 acc[4][3];
  #pragma unroll
  for (int m = 0; m < 4; ++m)
    #pragma unroll
    for (int n = 0; n < 3; ++n) acc[m][n] = (f32x4){0,0,0,0};

  f32x4 pa[4];
  s16x8 bE[3], bO[3];

  #define A_ISS(CH) do { _Pragma("unroll") for (int i_ = 0; i_ < 4; ++i_) \
      pa[i_] = rok[i_] ? *(const f32x4*)(xs + (size_t)(64 * i_) * HID + (CH) * BK) \
                       : (f32x4){0,0,0,0}; } while(0)

  #define A_WRT(BUF) do { _Pragma("unroll") for (int i_ = 0; i_ < 4; ++i_) \
      *(s16x4*)((char*)Abuf + (BUF) * 32768 + wofs + i_ * 8192) = pack4(pa[i_]); } while(0)

  #define BARRIER() do {                                           \
      asm volatile("s_waitcnt lgkmcnt(0)" ::: "memory");           \
      __builtin_amdgcn_s_barrier(); } while(0)

  // prologue: A chunk 0 staged; A chunk 1 + B(t=0) in flight
  A_ISS(0);
  A_WRT(0);
  A_ISS(1);
  #pragma unroll
  for (int n = 0; n < 3; ++n) bE[n] = loadB(n, 0);
  BARRIER();

  // K loop: r9 CHUNK structure verbatim (depth-1 A prefetch, kk-granular
  // B register pipeline, raw barrier -> loads stay in flight)
  #define CHUNK(C) do {                                                      \
    const int bufi = (C) & 1;                                                \
    const char* ab = abase + bufi * 32768;                                   \
    _Pragma("unroll")                                                        \
    for (int n = 0; n < 3; ++n) bO[n] = loadB(n, (C) * 2 + 1);               \
    {                                                                        \
      s16x8 a0 = *(const s16x8*)(ab + 0 * 2048 + col0);                      \
      s16x8 a1 = *(const s16x8*)(ab + 1 * 2048 + col0);                      \
      s16x8 a2 = *(const s16x8*)(ab + 2 * 2048 + col0);                      \
      s16x8 a3 = *(const s16x8*)(ab + 3 * 2048 + col0);                      \
      __builtin_amdgcn_s_setprio(1);                                         \
      _Pragma("unroll")                                                      \
      for (int n = 0; n < 3; ++n) {                                          \
        acc[0][n] = __builtin_amdgcn_mfma_f32_16x16x32_bf16(a0, bE[n], acc[0][n], 0,0,0); \
        acc[1][n] = __builtin_amdgcn_mfma_f32_16x16x32_bf16(a1, bE[n], acc[1][n], 0,0,0); \
        acc[2][n] = __builtin_amdgcn_mfma_f32_16x16x32_bf16(a2, bE[n], acc[2][n], 0,0,0); \
        acc[3][n] = __builtin_amdgcn_mfma_f32_16x16x32_bf16(a3, bE[n], acc[3][n], 0,0,0); \
      }                                                                      \
      __builtin_amdgcn_s_setprio(0);                                         \
    }                                                                        \
    {                                                                        \
      const int tn = (C) * 2 + 2;                                            \
      _Pragma("unroll")                                                      \
      for (int n = 0; n < 3; ++n) bE[n] = loadB(n, tn < 24 ? tn : 23);       \
      s16x8 a0 = *(const s16x8*)(ab + 0 * 2048 + col1);                      \
      s16x8 a1 = *(const s16x8*)(ab + 1 * 2048 + col1);                      \
      s16x8 a2 = *(const s16x8*)(ab + 2 * 2048 + col1);                      \
      s16x8 a3 = *(const s16x8*)(ab + 3 * 2048 + col1);                      \
      __builtin_amdgcn_s_setprio(1);                                         \
      _Pragma("unroll")                                                      \
      for (int n = 0; n < 3; ++n) {                                          \
        acc[0][n] = __builtin_amdgcn_mfma_f32_16x16x32_bf16(a0, bO[n], acc[0][n], 0,0,0); \
        acc[1][n] = __builtin_amdgcn_mfma_f32_16x16x32_bf16(a1, bO[n], acc[1][n], 0,0,0); \
        acc[2][n] = __builtin_amdgcn_mfma_f32_16x16x32_bf16(a2, bO[n], acc[2][n], 0,0,0); \
        acc[3][n] = __builtin_amdgcn_mfma_f32_16x16x32_bf16(a3, bO[n], acc[3][n], 0,0,0); \
      }                                                                      \
      __builtin_amdgcn_s_setprio(0);                                         \
    }                                                                        \
    if ((C) + 1 < NCH) A_WRT(bufi ^ 1);                                      \
    if ((C) + 2 < NCH) A_ISS((C) + 2);                                       \
    BARRIER();                                                               \
  } while(0)

  #pragma unroll 1
  for (int ch = 0; ch < NCH; ++ch) CHUNK(ch);

  // --- tanh + scorer dot (wave's 48 cols of this strip) -> s_lds ---
  float wv[3], bv[3];
  #pragma unroll
  for (int n = 0; n < 3; ++n) {
    int col = strip * 192 + nw * 48 + n * 16 + l15;
    wv[n] = scw[col];
    bv[n] = bias[col];
  }
  #pragma unroll
  for (int m = 0; m < 4; ++m) {
    #pragma unroll
    for (int r = 0; r < 4; ++r) {
      float v = 0.0f;
      #pragma unroll
      for (int n = 0; n < 3; ++n)
        v += fast_tanh(acc[m][n][r] + bv[n]) * wv[n];
      v += __shfl_xor(v, 1);
      v += __shfl_xor(v, 2);
      v += __shfl_xor(v, 4);
      v += __shfl_xor(v, 8);
      if (l15 == 0) atomicAdd(&s_lds[mw * 64 + m * 16 + lk * 4 + r], v);
    }
  }
  __syncthreads();

  // publish strip partials, counter handshake (r11/r13-verified)
  if (tid < nrows) atomicAdd(&s_glob[r0 + tid], s_lds[tid]);
  __syncthreads();
  if (tid == 0) {
    __threadfence();
    int old = atomicAdd(&cnt[tile], 1);
    lastflag = (old == NSTRIP - 1) ? 1 : 0;
  }
  __syncthreads();
  if (!lastflag) return;
  __threadfence();

  if (tid < MROWS)
    s_lds[tid] = (tid < nrows)
        ? __hip_atomic_load(&s_glob[r0 + tid], __ATOMIC_RELAXED, __HIP_MEMORY_SCOPE_AGENT)
        : 0.0f;
  __syncthreads();

  // --- per-word softmax + weighted sum (x L2/L3-warm), 16 waves x 4 words ---
  const float LOG2E = 1.4426950408889634f;
  for (int wi = wave; wi < WPB; wi += 16) {
    int gw = w0 + wi;
    if (gw >= num_words) break;
    int grs = mapping[2 * gw];
    int lrs = grs - r0;
    int cnt_ = min(mapping[2 * gw + 1] - r0, nrows) - lrs;
    float mmax = -3.0e38f;
    for (int i = 0; i < cnt_; ++i) mmax = fmaxf(mmax, s_lds[lrs + i]);
    float denom = 0.0f;
    for (int i = 0; i < cnt_; ++i) denom += exp2f((s_lds[lrs + i] - mmax) * LOG2E);
    float rden = (denom > 0.0f) ? (1.0f / denom) : 0.0f;
    float pbuf[8];
    #pragma unroll
    for (int i = 0; i < 8; ++i)
      pbuf[i] = (i < cnt_) ? exp2f((s_lds[lrs + i] - mmax) * LOG2E) * rden : 0.0f;
    #pragma unroll
    for (int j = 0; j < 3; ++j) {
      int col = j * 256 + lane * 4;
      const float* xb = x + (size_t)grs * HID + col;
      f32x4 o = {0, 0, 0, 0};
      #pragma unroll
      for (int i = 0; i < 8; ++i) {
        if (i < cnt_) {
          f32x4 xv = *(const f32x4*)(xb + (size_t)i * HID);
          o[0] += pbuf[i] * xv[0];
          o[1] += pbuf[i] * xv[1];
          o[2] += pbuf[i] * xv[2];
          o[3] += pbuf[i] * xv[3];
        }
      }
      for (int i = 8; i < cnt_; ++i) {   // generality tail (unused for this data)
        float p = exp2f((s_lds[lrs + i] - mmax) * LOG2E) * rden;
        f32x4 xv = *(const f32x4*)(xb + (size_t)i * HID);
        o[0] += p * xv[0];
        o[1] += p * xv[1];
        o[2] += p * xv[2];
        o[3] += p * xv[3];
      }
      *(f32x4*)(out + (size_t)gw * HID + col) = o;
    }
  }
  #undef A_ISS
  #undef A_WRT
  #undef BARRIER
  #undef CHUNK
}

// ==== fallback (fused 64-row kernel, fp32-B path) if workspace too small ====
__global__ __launch_bounds__(1024, 1) void fused_fb(
    const float* __restrict__ x, const float* __restrict__ Wf,
    const float* __restrict__ bias, const float* __restrict__ scw,
    const int* __restrict__ mapping, float* __restrict__ out, int num_words)
{
  __shared__ short Abuf[64 * 64];
  __shared__ float s_lds[64];
  const int tid = threadIdx.x;
  const int tile = blockIdx.x;
  const int w0 = tile * 16;
  const int wlast = min(w0 + 15, num_words - 1);
  const int r0 = mapping[2 * w0];
  const int r1 = mapping[2 * wlast + 1];
  const int nrows = min(r1 - r0, 64);
  const int srow = tid >> 4;
  const int sslot = tid & 15;
  const bool sok = srow < nrows;
  const float* xs = x + (size_t)(r0 + srow) * HID + sslot * 4;
  char* wsw = (char*)Abuf + srow * 128 + ((sslot * 8) ^ ((srow & 7) << 4));
  if (tid < 64) s_lds[tid] = 0.0f;
  const int lane = tid & 63;
  const int wave = tid >> 6;
  const int l15 = lane & 15;
  const int lk  = lane >> 4;
  const int c0  = wave * 48;
  const char* abase = (const char*)Abuf + l15 * 128;
  const int col0 = (lk * 16) ^ ((l15 & 7) << 4);
  const int col1 = col0 ^ 64;
  const float* Bf = Wf + (size_t)(c0 + l15) * HID + lk * 8;
  f32x4 acc[4][3];
  #pragma unroll
  for (int m = 0; m < 4; ++m)
    #pragma unroll
    for (int n = 0; n < 3; ++n) acc[m][n] = (f32x4){0,0,0,0};
  #pragma unroll 1
  for (int ch = 0; ch < NCH; ++ch) {
    f32x4 pfA = sok ? *(const f32x4*)(xs + ch * 64) : (f32x4){0,0,0,0};
    *(s16x4*)(wsw) = pack4(pfA);
    __syncthreads();
    #pragma unroll
    for (int kk = 0; kk < 2; ++kk) {
      const int kg = ch * 64 + kk * 32;
      s16x8 b[3];
      #pragma unroll
      for (int n = 0; n < 3; ++n) {
        f32x4 g0 = *(const f32x4*)(Bf + n * (16 * HID) + kg);
        f32x4 g1 = *(const f32x4*)(Bf + n * (16 * HID) + kg + 4);
        b[n] = pack8(g0, g1);
      }
      #pragma unroll
      for (int m = 0; m < 4; ++m) {
        s16x8 a = *(const s16x8*)(abase + m * 2048 + (kk ? col1 : col0));
        #pragma unroll
        for (int n = 0; n < 3; ++n)
          acc[m][n] = __builtin_amdgcn_mfma_f32_16x16x32_bf16(a, b[n], acc[m][n], 0,0,0);
      }
    }
    __syncthreads();
  }
  float wv[3], bv[3];
  #pragma unroll
  for (int n = 0; n < 3; ++n) {
    int col = c0 + n * 16 + l15;
    wv[n] = scw[col];
    bv[n] = bias[col];
  }
  #pragma unroll
  for (int m = 0; m < 4; ++m) {
    #pragma unroll
    for (int r = 0; r < 4; ++r) {
      float v = 0.0f;
      #pragma unroll
      for (int n = 0; n < 3; ++n)
        v += fast_tanh(acc[m][n][r] + bv[n]) * wv[n];
      v += __shfl_xor(v, 1);
      v += __shfl_xor(v, 2);
      v += __shfl_xor(v, 4);
      v += __shfl_xor(v, 8);
      if (l15 == 0) atomicAdd(&s_lds[m * 16 + lk * 4 + r], v);
    }
  }
  __syncthreads();
  const float LOG2E = 1.4426950408889634f;
  int gw = w0 + wave;
  if (wave < 16 && gw < num_words) {
    int grs = mapping[2 * gw];
    int lrs = grs - r0;
    int cnt_ = min(mapping[2 * gw + 1] - r0, nrows) - lrs;
    float mmax = -3.0e38f;
    for (int i = 0; i < cnt_; ++i) mmax = fmaxf(mmax, s_lds[lrs + i]);
    float denom = 0.0f;
    for (int i = 0; i < cnt_; ++i) denom += exp2f((s_lds[lrs + i] - mmax) * LOG2E);
    float rden = (denom > 0.0f) ? (1.0f / denom) : 0.0f;
    #pragma unroll
    for (int j = 0; j < 3; ++j) {
      int col = j * 256 + lane * 4;
      const float* xb = x + (size_t)grs * HID + col;
      f32x4 o = {0, 0, 0, 0};
      for (int i = 0; i < cnt_; ++i) {
        float p = exp2f((s_lds[lrs + i] - mmax) * LOG2E) * rden;
        f32x4 xv = *(const f32x4*)(xb + (size_t)i * HID);
        o[0] += p * xv[0]; o[1] += p * xv[1]; o[2] += p * xv[2]; o[3] += p * xv[3];
      }
      *(f32x4*)(out + (size_t)gw * HID + col) = o;
    }
  }
}

extern "C" void kernel_launch(void* const* d_in, const int* in_sizes, int n_in,
                              void* d_out, int out_size, void* d_ws, size_t ws_size,
                              hipStream_t stream) {
  const float* x    = (const float*)d_in[0];
  const float* W    = (const float*)d_in[1];
  const float* bias = (const float*)d_in[2];
  const float* scw  = (const float*)d_in[3];
  // d_in[4] (scorer bias) shifts every logit equally -> cancels in softmax
  const int* mapping = (const int*)d_in[5];
  float* out = (float*)d_out;

  int num_words = in_sizes[5] / 2;
  int n_sub = in_sizes[0] / HID;
  int ntiles = (num_words + WPB - 1) / WPB;

  size_t wb_bytes  = (size_t)HID * HID * sizeof(short);
  size_t sg_bytes  = (size_t)n_sub * sizeof(float);
  size_t cnt_bytes = (size_t)ntiles * sizeof(int);
  size_t need = wb_bytes + sg_bytes + cnt_bytes;

  char* wsb = (char*)d_ws;
  if (ws_size >= need) {
    short* Wb     = (short*)wsb;
    float* s_glob = (float*)(wsb + wb_bytes);
    int*   cntb   = (int*)(wsb + wb_bytes + sg_bytes);
    hipMemsetAsync(s_glob, 0, sg_bytes + cnt_bytes, stream);
    int n64 = (HID / 32) * (HID / 16) * 64;
    wconv_kernel<<<(n64 + 255) / 256, 256, 0, stream>>>(W, Wb, n64);
    int swz = (ntiles % 8 == 0) ? 1 : 0;
    gemm_m256<<<ntiles * NSTRIP, 1024, 0, stream>>>(
        x, Wb, bias, scw, mapping, out, num_words, s_glob, cntb, swz);
  } else {
    int nt16 = (num_words + 15) / 16;
    fused_fb<<<nt16, 1024, 0, stream>>>(x, W, bias, scw, mapping, out, num_words);
  }
}